// Round 15
// baseline (151.927 us; speedup 1.0000x reference)
//
#include <hip/hip_runtime.h>
#include <hip/hip_bf16.h>
#include <cstdint>
#include <cstddef>

#define IN_F   1024
#define OUT_F  1024
#define NB     8            // KNOT_COUNT + ORDER = 5 + 3
#define BATCH  4096
#define KTOT   (NB * IN_F)  // 8192

typedef __attribute__((ext_vector_type(4)))  float  f32x4;
typedef __attribute__((ext_vector_type(8)))  float  f32x8;
typedef __attribute__((ext_vector_type(4)))  int    i32x4;

// async global->LDS, 16B per lane (LDS dest = wave-uniform base + lane*16)
#define GLDS16(g, l)                                                     \
    __builtin_amdgcn_global_load_lds(                                    \
        (const __attribute__((address_space(1))) void*)(g),              \
        (__attribute__((address_space(3))) void*)(l), 16, 0, 0)

#define FENCE() __builtin_amdgcn_sched_barrier(0)

// A-quant scale: basis values in [0, 2/3]; 190.5 = 127/(2/3) -> q in [0,127]
#define SA 190.5f

// uniform cubic B-spline weights at r in [0,1)
__device__ __forceinline__ void spline_w(float r, float w[4]) {
    const float r2 = r * r, r3 = r2 * r;
    const float omr = 1.0f - r;
    w[0] = omr * omr * omr * (1.0f / 6.0f);
    w[1] = (3.0f * r3 - 6.0f * r2 + 4.0f) * (1.0f / 6.0f);
    w[2] = (-3.0f * r3 + 3.0f * r2 + 3.0f * r + 1.0f) * (1.0f / 6.0f);
    w[3] = r3 * (1.0f / 6.0f);
}

// ---------------------------------------------------------------------------
// fused prep (i8):
//  blocks [0,2048): W quant.  One wave per (n,o) row: load 1024 f32 (16/lane),
//    wave-reduce absmax, quantize to i8, store 16B/lane; sW[row] holds the
//    folded dequant factor absmax/(127*190.5).
//  blocks [2048,4096): basis A8[b][n*1024+i] = round(B_n(x)*190.5), i8.
//    8 i's/thread -> one 8B store per basis n.  No swizzle needed: i8 GEMM
//    LDS rows are 64B (conflict-free by construction).
// ---------------------------------------------------------------------------
__global__ void k_prep(const float* __restrict__ coeffs, signed char* __restrict__ W8,
                       float* __restrict__ sW,
                       const float* __restrict__ x, signed char* __restrict__ A8) {
    const int bb  = blockIdx.x;
    const int tid = threadIdx.x;
    if (bb < 2048) {
        const int r    = bb * 4 + (tid >> 6);   // row 0..8191 = n*1024 + o
        const int lane = tid & 63;
        const float* src = coeffs + (size_t)r * 1024 + lane * 16;
        f32x4 v[4];
#pragma unroll
        for (int e = 0; e < 4; ++e) v[e] = ((const f32x4*)src)[e];
        float am = 0.0f;
#pragma unroll
        for (int e = 0; e < 4; ++e)
#pragma unroll
            for (int j = 0; j < 4; ++j) am = fmaxf(am, fabsf(v[e][j]));
#pragma unroll
        for (int m = 1; m < 64; m <<= 1) am = fmaxf(am, __shfl_xor(am, m));
        am = fmaxf(am, 1e-20f);
        const float inv = 127.0f / am;
        i32x4 o;
#pragma unroll
        for (int e = 0; e < 4; ++e) {
            unsigned int u = 0;
#pragma unroll
            for (int j = 0; j < 4; ++j) {
                const int q = (int)__builtin_rintf(v[e][j] * inv);
                u |= ((unsigned int)(q & 255)) << (8 * j);
            }
            o[e] = (int)u;
        }
        *(i32x4*)(W8 + (size_t)r * 1024 + lane * 16) = o;
        if (lane == 0) sW[r] = am / (127.0f * SA);
    } else {
        const int g    = (bb - 2048) * blockDim.x + tid;
        const int flat = g * 8;                       // [b][i] flat, i fastest
        const int b = flat >> 10, i = flat & 1023;    // i aligned to 8
        f32x8 xv = *(const f32x8*)(x + flat);

        float w[8][4];
        int   jj[8];
#pragma unroll
        for (int e = 0; e < 8; ++e) {
            const float u  = (xv[e] + 2.5f) * 2.0f;   // knots [-1,1], h=0.5
            const float jf = floorf(u);
            jj[e] = (int)jf;
            spline_w(u - jf, w[e]);
        }

        signed char* base = A8 + (size_t)b * KTOT + i;
#pragma unroll
        for (int n = 0; n < NB; ++n) {
            unsigned long long u64 = 0;
#pragma unroll
            for (int e = 0; e < 8; ++e) {
                const int d = n - jj[e] + 3;          // which of the 4 weights
                float v = (d == 0) ? w[e][0]
                        : (d == 1) ? w[e][1]
                        : (d == 2) ? w[e][2]
                        : (d == 3) ? w[e][3] : 0.0f;
                const int q = (int)__builtin_rintf(v * SA);
                u64 |= ((unsigned long long)(q & 255)) << (8 * e);
            }
            *(unsigned long long*)(base + n * IN_F) = u64;   // 8B store
        }
    }
}

// ---------------------------------------------------------------------------
// i8 GEMM, split-K x2 (r5-verified skeleton; i8 halves MFMA count, LDS reads,
// staging bytes):  C[4096][1024] = dequant( A8[4096][8192] * W8^T ).
// BM=256, BN=128, BK=64; 512 threads = 8 waves (4M x 2N), wave 64x64
// (mfma_i32_16x16x64_i8: one MFMA covers K=64 -> 16 MFMA + 8 ds_read_b128
// per wave per K-tile).  i32 acc per n-slice (16 K-tiles), rescaled into f32
// acc with folded scale sW[n][col]/190.5 at each slice boundary (scales are
// col-uniform per acc vector; C/D layout dtype-independent, m121-128).
// 3-deep LDS pipeline (24KB/buf, 72KB), counted vmcnt(3) (tile t+1 in
// flight; never drained mid-loop).  XCD-aware decode.  i8 rows are 64B ->
// wave frag reads are 1KB contiguous -> conflict-free, NO swizzle.
// kz=0 -> C, kz=1 -> P partial; k_add reduces (atomics regressed, r13).
// ---------------------------------------------------------------------------
#define BM 256
#define BN 128
#define BK 64
#define NT (KTOT / BK)     // 128
#define SPLITK 2
#define NTS (NT / SPLITK)  // 64
#define BUFSZ 24576        // A 16K | B 8K

__global__ __launch_bounds__(512, 4) void k_gemm(const signed char* __restrict__ A8,
                                                 const signed char* __restrict__ W8,
                                                 const float* __restrict__ sW,
                                                 float* __restrict__ C,
                                                 float* __restrict__ P) {
    __shared__ __align__(16) char ls[3 * BUFSZ];   // 72 KiB

    // XCD-aware decode: fid&7 = XCD; same-y blocks colocate.
    const int fid = blockIdx.x;
    const int xcd = fid & 7;
    const int s   = fid >> 3;            // 0..31
    const int y   = xcd + 8 * (s & 1);   // 0..15  (A row-panel)
    const int xb  = (s >> 1) & 7;        // 0..7   (W col-panel)
    const int kz  = s >> 4;              // 0..1   (K split)

    const int o0   = xb * BN;
    const int b0   = y * BM;
    const int tid  = threadIdx.x;
    const int lane = tid & 63;
    const int wv   = tid >> 6;
    const int wr   = wv >> 1;          // wave row (0..3)
    const int wc   = wv & 1;           // wave col (0..1)
    const int l15  = lane & 15;
    const int lhi  = lane >> 4;        // 0..3  (K quarter: 16 i8 each)

    f32x4 accf[4][4] = {};
    i32x4 acci[4][4] = {};

    const int srow = tid >> 2;         // 0..127
    const int scol = (tid & 3) * 16;   // byte col within 64B k-row

    auto STAGE = [&](int buf, int kt) {
        const int k0 = kt * BK;        // i8: byte offset == element offset
        const int n  = k0 >> 10;
        const int i0 = k0 & 1023;
        char* la = ls + buf * BUFSZ;
        char* lb = la + 16384;
        GLDS16(A8 + (size_t)(b0 + srow) * KTOT + k0 + scol,       la + tid * 16);
        GLDS16(A8 + (size_t)(b0 + srow + 128) * KTOT + k0 + scol, la + tid * 16 + 8192);
        GLDS16(W8 + ((size_t)n << 20) + (size_t)(o0 + srow) * IN_F + i0 + scol,
               lb + tid * 16);
    };

    // preload folded dequant scales: sWr[slice][nn] for this lane's columns
    float sWr[4][4];
#pragma unroll
    for (int sl = 0; sl < 4; ++sl)
#pragma unroll
        for (int nn = 0; nn < 4; ++nn)
            sWr[sl][nn] = sW[(size_t)(kz * 4 + sl) * 1024
                             + o0 + wc * 64 + nn * 16 + l15];
    FENCE();
    asm volatile("s_waitcnt vmcnt(0)" ::: "memory");  // drain scale loads
    FENCE();

    const int ktBeg = kz * NTS;
    STAGE(0, ktBeg);
    STAGE(1, ktBeg + 1);

    int cur = 0, nxt = 2;
#pragma unroll
    for (int sl = 0; sl < 4; ++sl) {                   // n-slice (16 K-tiles)
        for (int tt = 0; tt < 16; ++tt) {
            const int t = sl * 16 + tt;
            // counted wait: tile t landed; tile t+1's 3 loads stay in flight
            if (t < NTS - 1) asm volatile("s_waitcnt vmcnt(3)" ::: "memory");
            else             asm volatile("s_waitcnt vmcnt(0)" ::: "memory");
            __builtin_amdgcn_s_barrier();
            FENCE();

            if (t + 2 < NTS) STAGE(nxt, ktBeg + t + 2);

            const char* la = ls + cur * BUFSZ;
            const char* lb = la + 16384;
            i32x4 af[4], bfr[4];
#pragma unroll
            for (int m = 0; m < 4; ++m)
                af[m] = *(const i32x4*)(la + (wr * 64 + m * 16 + l15) * 64 + lhi * 16);
#pragma unroll
            for (int nn = 0; nn < 4; ++nn)
                bfr[nn] = *(const i32x4*)(lb + (wc * 64 + nn * 16 + l15) * 64 + lhi * 16);
            __builtin_amdgcn_s_setprio(1);
#pragma unroll
            for (int m = 0; m < 4; ++m)
#pragma unroll
                for (int nn = 0; nn < 4; ++nn)
                    acci[m][nn] = __builtin_amdgcn_mfma_i32_16x16x64_i8(
                        af[m], bfr[nn], acci[m][nn], 0, 0, 0);
            __builtin_amdgcn_s_setprio(0);
            cur = (cur == 2) ? 0 : cur + 1;
            nxt = (nxt == 2) ? 0 : nxt + 1;
        }
        // slice boundary: dequant-accumulate and reset i32 acc
#pragma unroll
        for (int m = 0; m < 4; ++m)
#pragma unroll
            for (int nn = 0; nn < 4; ++nn) {
                accf[m][nn] += __builtin_convertvector(acci[m][nn], f32x4)
                               * sWr[sl][nn];
                acci[m][nn] = (i32x4){0, 0, 0, 0};
            }
    }

    // epilogue: C/D layout col = lane&15, row = (lane>>4)*4 + reg
    float* dst = (kz == 0) ? C : P;
    const int crow = lhi * 4;
#pragma unroll
    for (int m = 0; m < 4; ++m) {
#pragma unroll
        for (int nn = 0; nn < 4; ++nn) {
            float* cp = dst + (size_t)(b0 + wr * 64 + m * 16 + crow) * OUT_F
                            + o0 + wc * 64 + nn * 16 + l15;
#pragma unroll
            for (int j = 0; j < 4; ++j)
                cp[(size_t)j * OUT_F] = accf[m][nn][j];
        }
    }
}

// C += P, vectorized
__global__ void k_add(float* __restrict__ C, const float* __restrict__ P) {
    const size_t g = (size_t)(blockIdx.x * blockDim.x + threadIdx.x) * 4;
    f32x4 a = *(const f32x4*)(C + g);
    f32x4 b = *(const f32x4*)(P + g);
    a += b;
    *(f32x4*)(C + g) = a;
}

// ---------------------------------------------------------------------------
// slow-but-correct fallback (only if ws too small): fp32, no workspace
// ---------------------------------------------------------------------------
__global__ void k_naive(const float* __restrict__ x, const float* __restrict__ coeffs,
                        float* __restrict__ out) {
    const int b = blockIdx.y * 16 + (threadIdx.x >> 4);
    const int o = blockIdx.x * 16 + (threadIdx.x & 15);
    float sum = 0.0f;
    for (int i = 0; i < IN_F; ++i) {
        const float u  = (x[(size_t)b * IN_F + i] + 2.5f) * 2.0f;
        const float jf = floorf(u);
        const int   j  = (int)jf;
        float w[4];
        spline_w(u - jf, w);
#pragma unroll
        for (int m = 0; m < 4; ++m) {
            const int idx = j - 3 + m;
            if (idx >= 0 && idx < NB)
                sum += w[m] * coeffs[(size_t)idx * OUT_F * IN_F + (size_t)o * IN_F + i];
        }
    }
    out[(size_t)b * OUT_F + o] = sum;
}

// ---------------------------------------------------------------------------
extern "C" void kernel_launch(void* const* d_in, const int* in_sizes, int n_in,
                              void* d_out, int out_size, void* d_ws, size_t ws_size,
                              hipStream_t stream) {
    const float* x      = (const float*)d_in[0];
    // d_in[1] = knots: fixed linspace(-1,1,5) -> folded into constants
    const float* coeffs = (const float*)d_in[2];
    float* out = (float*)d_out;

    const size_t needA = (size_t)BATCH * KTOT;            // 32 MiB (i8)
    const size_t needW = (size_t)NB * OUT_F * IN_F;       // 8 MiB (i8)
    const size_t needS = (size_t)NB * OUT_F * sizeof(float); // 32 KiB
    const size_t oneP  = (size_t)BATCH * OUT_F * sizeof(float); // 16 MiB

    if (ws_size >= needA + needW + needS + oneP) {
        signed char* A8 = (signed char*)d_ws;
        signed char* W8 = (signed char*)((char*)d_ws + needA);
        float*       sW = (float*)((char*)d_ws + needA + needW);
        float*       P  = (float*)((char*)d_ws + needA + needW + needS);

        hipLaunchKernelGGL(k_prep, dim3(4096), dim3(256), 0, stream,
                           coeffs, W8, sW, x, A8);
        hipLaunchKernelGGL(k_gemm, dim3(256), dim3(512), 0, stream,
                           A8, W8, sW, out, P);
        hipLaunchKernelGGL(k_add, dim3(BATCH * OUT_F / 4 / 256), dim3(256),
                           0, stream, out, P);
    } else {
        hipLaunchKernelGGL(k_naive, dim3(OUT_F / 16, BATCH / 16), dim3(256), 0,
                           stream, x, coeffs, out);
    }
}